// Round 1
// baseline (162.045 us; speedup 1.0000x reference)
//
#include <hip/hip_runtime.h>
#include <hip/hip_bf16.h>
#include <cstdint>
#include <cstddef>

#define HDIM 512
#define NEXP 8

typedef __bf16 bf16t;
typedef __attribute__((ext_vector_type(8))) __bf16 bf16x8;
typedef __attribute__((ext_vector_type(4))) __bf16 bf16x4;
typedef __attribute__((ext_vector_type(4))) float f32x4;

__device__ inline void gload_lds16(const void* g, void* l) {
  __builtin_amdgcn_global_load_lds(
      (const __attribute__((address_space(1))) void*)g,
      (__attribute__((address_space(3))) void*)l, 16, 0, 0);
}

// ---------------- zero output ----------------
__global__ void k_zero(float4* __restrict__ p, int n4) {
  int i = blockIdx.x * blockDim.x + threadIdx.x;
  int st = gridDim.x * blockDim.x;
  for (; i < n4; i += st) p[i] = make_float4(0.f, 0.f, 0.f, 0.f);
}

// ---------------- init counters ----------------
__global__ void k_init(int* __restrict__ counts) {
  if (threadIdx.x < NEXP) counts[threadIdx.x] = 0;
}

// ---------------- W[e][h][o] f32 -> wT[e][o][h] bf16 (transpose+convert) ----
__global__ void k_wt(const float* __restrict__ W, bf16t* __restrict__ wT) {
  __shared__ float t[64][65];
  int b = blockIdx.x;
  int e = b >> 6, ht = (b >> 3) & 7, ot = b & 7;
  const float* We = W + (size_t)e * HDIM * HDIM;
  int tid = threadIdx.x;
  int c = tid & 63, rr = tid >> 6;  // 4 rows per pass
#pragma unroll
  for (int i = 0; i < 16; ++i) {
    int h = i * 4 + rr;
    t[h][c] = We[(size_t)(ht * 64 + h) * HDIM + ot * 64 + c];
  }
  __syncthreads();
  bf16t* dst = wT + (size_t)e * HDIM * HDIM;
#pragma unroll
  for (int i = 0; i < 16; ++i) {
    int o = i * 4 + rr;
    dst[(size_t)(ot * 64 + o) * HDIM + ht * 64 + c] = (bf16t)t[c][o];
  }
}

// ---------------- router: logits fp32, softmax, top-2, weights, counts ------
__global__ void k_router(const float* __restrict__ x, const float* __restrict__ rw,
                         int* __restrict__ idx0, int* __restrict__ idx1,
                         float* __restrict__ w0, float* __restrict__ w1,
                         int* __restrict__ counts, int ntok) {
  __shared__ int lcnt[NEXP];
  int tid = threadIdx.x;
  if (tid < NEXP) lcnt[tid] = 0;
  __syncthreads();
  int wv = tid >> 6, lane = tid & 63;
  int g = lane >> 3, r = lane & 7;  // expert group, lane-in-group
  const float4* wrow = (const float4*)(rw + g * HDIM);
  for (int it = 0; it < 8; ++it) {
    int n = blockIdx.x * 32 + wv * 8 + it;
    if (n >= ntok) break;
    const float4* xrow = (const float4*)(x + (size_t)n * HDIM);
    float acc = 0.f;
#pragma unroll
    for (int t = 0; t < 16; ++t) {
      float4 xv = xrow[t * 8 + r];
      float4 wvv = wrow[t * 8 + r];
      acc += xv.x * wvv.x + xv.y * wvv.y + xv.z * wvv.z + xv.w * wvv.w;
    }
    acc += __shfl_xor(acc, 1);
    acc += __shfl_xor(acc, 2);
    acc += __shfl_xor(acc, 4);  // every lane of group g now has logit[g]
    float lg[NEXP];
#pragma unroll
    for (int e = 0; e < NEXP; ++e) lg[e] = __shfl(acc, e * 8);
    float m = lg[0];
#pragma unroll
    for (int e = 1; e < NEXP; ++e) m = fmaxf(m, lg[e]);
    float p[NEXP];
    float S = 0.f;
#pragma unroll
    for (int e = 0; e < NEXP; ++e) { p[e] = expf(lg[e] - m); S += p[e]; }
    float inv = 1.f / S;
#pragma unroll
    for (int e = 0; e < NEXP; ++e) p[e] *= inv;
    // top-2 with lowest-index tie-break (strict >)
    int b0 = 0;
#pragma unroll
    for (int e = 1; e < NEXP; ++e) if (p[e] > p[b0]) b0 = e;
    int b1 = (b0 == 0) ? 1 : 0;
#pragma unroll
    for (int e = 0; e < NEXP; ++e) if (e != b0 && p[e] > p[b1]) b1 = e;
    float v0 = p[b0], v1 = p[b1];
    float s = v0 + v1 + 1e-6f;
    if (lane == 0) {
      idx0[n] = b0; idx1[n] = b1;
      w0[n] = v0 / s; w1[n] = v1 / s;
      atomicAdd(&lcnt[b0], 1);
      atomicAdd(&lcnt[b1], 1);
    }
  }
  __syncthreads();
  if (tid < NEXP && lcnt[tid] > 0) atomicAdd(&counts[tid], lcnt[tid]);
}

// ---------------- offsets: exclusive prefix over 8 counts -------------------
__global__ void k_offsets(const int* __restrict__ counts, int* __restrict__ offs,
                          int* __restrict__ cursor) {
  if (threadIdx.x == 0) {
    int s = 0;
    for (int e = 0; e < NEXP; ++e) { offs[e] = s; cursor[e] = s; s += counts[e]; }
  }
}

// ---------------- scatter tokens into per-expert buckets --------------------
__global__ void k_scatter(const int* __restrict__ idx0, const int* __restrict__ idx1,
                          const float* __restrict__ w0, const float* __restrict__ w1,
                          int* __restrict__ cursor, int* __restrict__ btok,
                          float* __restrict__ bw, int ntok) {
  __shared__ int lcnt[NEXP], lbase[NEXP];
  int tid = threadIdx.x;
  if (tid < NEXP) lcnt[tid] = 0;
  __syncthreads();
  int n = blockIdx.x * 64 + tid;
  int e0 = 0, e1 = 0, p0 = 0, p1 = 0;
  float a0 = 0.f, a1 = 0.f;
  bool act = (n < ntok);
  if (act) {
    e0 = idx0[n]; e1 = idx1[n]; a0 = w0[n]; a1 = w1[n];
    p0 = atomicAdd(&lcnt[e0], 1);
    p1 = atomicAdd(&lcnt[e1], 1);
  }
  __syncthreads();
  if (tid < NEXP) lbase[tid] = lcnt[tid] ? atomicAdd(&cursor[tid], lcnt[tid]) : 0;
  __syncthreads();
  if (act) {
    int q0 = lbase[e0] + p0; btok[q0] = n; bw[q0] = a0;
    int q1 = lbase[e1] + p1; btok[q1] = n; bw[q1] = a1;
  }
}

// ---------------- grouped GEMM: per expert, gathered rows of x --------------
// Tile 128x128, BK=32, 4 waves (2x2), mfma_f32_16x16x32_bf16.
// A (tokens x K): gathered from x (fp32) with in-register f32->bf16 convert.
// B (K x N): wT[e][n][k] bf16, K-contiguous, staged via global_load_lds(16B).
__global__ __launch_bounds__(256, 2) void k_gemm(
    const float* __restrict__ x, const bf16t* __restrict__ wT,
    const int* __restrict__ btok, const float* __restrict__ bw,
    const int* __restrict__ counts, const int* __restrict__ offs,
    float* __restrict__ out, int rtPerE) {
  __shared__ bf16t Asm[128 * 32];  // [row][k] 8KB
  __shared__ bf16t Bsm[128 * 32];  // [n][k]   8KB
  int bid = blockIdx.x;
  int tilesPerE = rtPerE * 4;
  int e = bid / tilesPerE;
  int rem = bid - e * tilesPerE;
  int rt = rem >> 2;
  int ct = rem & 3;
  int cnt = counts[e];
  int m0 = rt << 7;
  if (m0 >= cnt) return;
  int off = offs[e];
  int n0 = ct << 7;
  int tid = threadIdx.x;
  int lane = tid & 63;
  int wv = tid >> 6, wr = wv >> 1, wc = wv & 1;

  // A staging: 4 issues; issue i covers row i*32 + tid/8, chunk tid%8 (float4)
  const float* asrc[4];
  int aldsoff[4];
  {
    int arow_c = tid >> 3, achk = tid & 7;
#pragma unroll
    for (int i = 0; i < 4; ++i) {
      int rrow = i * 32 + arow_c;
      int gr = m0 + rrow;
      if (gr > cnt - 1) gr = cnt - 1;  // clamp ragged tail (stores are guarded)
      int tok = btok[off + gr];
      asrc[i] = x + (size_t)tok * HDIM + achk * 4;
      aldsoff[i] = rrow * 32 + achk * 4;
    }
  }
  // B staging: 2 issues; issue i covers row i*64 + tid/4, chunk tid%4 (8 bf16)
  const bf16t* bsrc[2];
  {
    int brow_c = tid >> 2, bchk = tid & 3;
#pragma unroll
    for (int i = 0; i < 2; ++i) {
      int rrow = i * 64 + brow_c;
      bsrc[i] = wT + (size_t)(e * HDIM + n0 + rrow) * HDIM + bchk * 8;
    }
  }

  f32x4 acc[4][4];
#pragma unroll
  for (int a = 0; a < 4; ++a)
#pragma unroll
    for (int b = 0; b < 4; ++b) acc[a][b] = f32x4{0.f, 0.f, 0.f, 0.f};

  int aro = (wr * 64 + (lane & 15)) * 32 + (lane >> 4) * 8;
  int bro = (wc * 64 + (lane & 15)) * 32 + (lane >> 4) * 8;

  for (int kt = 0; kt < HDIM / 32; ++kt) {
    int k0 = kt * 32;
#pragma unroll
    for (int i = 0; i < 2; ++i)
      gload_lds16(bsrc[i] + k0, Bsm + i * 2048 + tid * 8);
#pragma unroll
    for (int i = 0; i < 4; ++i) {
      float4 v = *(const float4*)(asrc[i] + k0);
      bf16x4 h;
      h[0] = (bf16t)v.x; h[1] = (bf16t)v.y; h[2] = (bf16t)v.z; h[3] = (bf16t)v.w;
      *(bf16x4*)(Asm + aldsoff[i]) = h;
    }
    __syncthreads();  // drains vmcnt (global_load_lds) + lgkm (ds_write)
    bf16x8 af[4], bfr[4];
#pragma unroll
    for (int mi = 0; mi < 4; ++mi)
      af[mi] = *(const bf16x8*)(Asm + aro + mi * 16 * 32);
#pragma unroll
    for (int ni = 0; ni < 4; ++ni)
      bfr[ni] = *(const bf16x8*)(Bsm + bro + ni * 16 * 32);
#pragma unroll
    for (int mi = 0; mi < 4; ++mi)
#pragma unroll
      for (int ni = 0; ni < 4; ++ni)
        acc[mi][ni] =
            __builtin_amdgcn_mfma_f32_16x16x32_bf16(af[mi], bfr[ni], acc[mi][ni], 0, 0, 0);
    __syncthreads();
  }

  // Epilogue: D[row][col]: col = lane&15, row = (lane>>4)*4 + j  [m89/m91]
  int col0 = n0 + wc * 64 + (lane & 15);
  int rbase = m0 + wr * 64 + ((lane >> 4) << 2);
#pragma unroll
  for (int mi = 0; mi < 4; ++mi) {
#pragma unroll
    for (int j = 0; j < 4; ++j) {
      int rrow = rbase + mi * 16 + j;
      if (rrow < cnt) {
        int tok = btok[off + rrow];
        float w = bw[off + rrow];
        float* orow = out + (size_t)tok * HDIM + col0;
#pragma unroll
        for (int ni = 0; ni < 4; ++ni)
          atomicAdd(orow + ni * 16, w * acc[mi][ni][j]);
      }
    }
  }
}

extern "C" void kernel_launch(void* const* d_in, const int* in_sizes, int n_in,
                              void* d_out, int out_size, void* d_ws, size_t ws_size,
                              hipStream_t stream) {
  const float* x = (const float*)d_in[0];
  const float* rw = (const float*)d_in[1];
  const float* W = (const float*)d_in[2];
  float* out = (float*)d_out;
  int ntok = in_sizes[0] / HDIM;  // 16384 for B=4,S=4096
  if (ntok <= 0) return;

  // workspace layout
  char* ws = (char*)d_ws;
  size_t o = 0;
  bf16t* wT = (bf16t*)(ws + o); o += (size_t)NEXP * HDIM * HDIM * sizeof(bf16t);
  int* idx0 = (int*)(ws + o); o += (size_t)ntok * 4;
  int* idx1 = (int*)(ws + o); o += (size_t)ntok * 4;
  float* w0 = (float*)(ws + o); o += (size_t)ntok * 4;
  float* w1 = (float*)(ws + o); o += (size_t)ntok * 4;
  int* counts = (int*)(ws + o); o += 256;
  int* offs = counts + 8;
  int* cursor = counts + 16;
  int* btok = (int*)(ws + o); o += (size_t)2 * ntok * 4;
  float* bw = (float*)(ws + o); o += (size_t)2 * ntok * 4;
  if (ws_size < o) return;  // need ~4.7 MB

  k_init<<<dim3(1), dim3(64), 0, stream>>>(counts);
  k_wt<<<dim3(512), dim3(256), 0, stream>>>(W, wT);
  k_router<<<dim3((ntok + 31) / 32), dim3(256), 0, stream>>>(x, rw, idx0, idx1, w0, w1,
                                                             counts, ntok);
  k_offsets<<<dim3(1), dim3(64), 0, stream>>>(counts, offs, cursor);
  k_scatter<<<dim3((ntok + 63) / 64), dim3(64), 0, stream>>>(idx0, idx1, w0, w1, cursor,
                                                             btok, bw, ntok);
  k_zero<<<dim3(2048), dim3(256), 0, stream>>>((float4*)out, ntok * HDIM / 4);
  int rtPerE = (ntok + 127) / 128;  // worst case: all tokens on one expert
  k_gemm<<<dim3(NEXP * rtPerE * 4), dim3(256), 0, stream>>>(x, wT, btok, bw, counts, offs,
                                                            out, rtPerE);
}